// Round 13
// baseline (65.751 us; speedup 1.0000x reference)
//
#include <hip/hip_runtime.h>
#include <math.h>

// GAT aggregator: out = relu( deg>0 ? segment_softmax(leaky(s_src[src]+s_dst[dst])) @ Wh[dst] : Wh )
// N=100000, E=1600000, D=64. edge_src is SORTED.
// wh: bf16 MFMA (16x16x32). agg: 8-lane group handles TWO nodes sequentially
// (g and g+H) to cut wave divergence; 4-wide ILP; bf16 rows (1 line/row).

#define DD 64

typedef __attribute__((ext_vector_type(8))) short bf16x8;
typedef __attribute__((ext_vector_type(4))) float f32x4;

static __device__ __forceinline__ unsigned short f2bf(float x) {
    unsigned int u = __float_as_uint(x);
    u += 0x7fffu + ((u >> 16) & 1u);          // RNE
    return (unsigned short)(u >> 16);
}

static __device__ __forceinline__ bf16x8 cvt8(float4 x0, float4 x1) {
    bf16x8 f;
    f[0] = (short)f2bf(x0.x); f[1] = (short)f2bf(x0.y);
    f[2] = (short)f2bf(x0.z); f[3] = (short)f2bf(x0.w);
    f[4] = (short)f2bf(x1.x); f[5] = (short)f2bf(x1.y);
    f[6] = (short)f2bf(x1.z); f[7] = (short)f2bf(x1.w);
    return f;
}

static __device__ __forceinline__ void fma8(float p, uint4 q, float* acc) {
    acc[0] = fmaf(p, __uint_as_float(q.x << 16),          acc[0]);
    acc[1] = fmaf(p, __uint_as_float(q.x & 0xffff0000u),  acc[1]);
    acc[2] = fmaf(p, __uint_as_float(q.y << 16),          acc[2]);
    acc[3] = fmaf(p, __uint_as_float(q.y & 0xffff0000u),  acc[3]);
    acc[4] = fmaf(p, __uint_as_float(q.z << 16),          acc[4]);
    acc[5] = fmaf(p, __uint_as_float(q.z & 0xffff0000u),  acc[5]);
    acc[6] = fmaf(p, __uint_as_float(q.w << 16),          acc[6]);
    acc[7] = fmaf(p, __uint_as_float(q.w & 0xffff0000u),  acc[7]);
}

// ---------------- Kernel 1: Whb = bf16(h @ W^T) via MFMA; s_src/s_dst from D-frags --
__global__ __launch_bounds__(256) void wh_kernel(
    const float* __restrict__ h, const float* __restrict__ W,
    const float* __restrict__ a, unsigned short* __restrict__ Whb,
    float* __restrict__ s_src, float* __restrict__ s_dst, int N)
{
    __shared__ unsigned short pack[4][16][72];   // per-wave repack buffer

    int w    = threadIdx.x >> 6;
    int lane = threadIdx.x & 63;
    int lr   = lane & 15;                        // row-in-tile (A) / col-in-tile (B,D)
    int lk   = lane >> 4;                        // k-group (A,B) / row-group (D)
    int m0   = blockIdx.x * 64 + w * 16;
    if (m0 >= N) return;                         // wave-uniform exit; no barriers used

    // B-frags: whole W (64x64) as 8 frags (t = col tile, q = k half)
    bf16x8 bfr[4][2];
    #pragma unroll
    for (int t = 0; t < 4; ++t) {
        const float* wrow = W + (size_t)(t * 16 + lr) * DD;
        #pragma unroll
        for (int q = 0; q < 2; ++q) {
            float4 x0 = *(const float4*)(wrow + q * 32 + lk * 8);
            float4 x1 = *(const float4*)(wrow + q * 32 + lk * 8 + 4);
            bfr[t][q] = cvt8(x0, x1);
        }
    }

    // A-frags: this wave's 16 h rows
    int arow = m0 + lr; if (arow >= N) arow = N - 1;
    const float* hrow = h + (size_t)arow * DD;
    bf16x8 afr[2];
    #pragma unroll
    for (int q = 0; q < 2; ++q) {
        float4 x0 = *(const float4*)(hrow + q * 32 + lk * 8);
        float4 x1 = *(const float4*)(hrow + q * 32 + lk * 8 + 4);
        afr[q] = cvt8(x0, x1);
    }

    // 8 MFMA: 4 col-tiles x K=64
    f32x4 acc[4];
    #pragma unroll
    for (int t = 0; t < 4; ++t) {
        f32x4 z = {0.f, 0.f, 0.f, 0.f};
        z = __builtin_amdgcn_mfma_f32_16x16x32_bf16(afr[0], bfr[t][0], z, 0, 0, 0);
        acc[t] = __builtin_amdgcn_mfma_f32_16x16x32_bf16(afr[1], bfr[t][1], z, 0, 0, 0);
    }

    // scores: lane has col = t*16+lr, rows lk*4+r
    float av0[4], av1[4];
    #pragma unroll
    for (int t = 0; t < 4; ++t) {
        av0[t] = a[t * 16 + lr];
        av1[t] = a[DD + t * 16 + lr];
    }
    #pragma unroll
    for (int r = 0; r < 4; ++r) {
        float ssrc = 0.f, sdst = 0.f;
        #pragma unroll
        for (int t = 0; t < 4; ++t) {
            ssrc = fmaf(acc[t][r], av0[t], ssrc);
            sdst = fmaf(acc[t][r], av1[t], sdst);
        }
        #pragma unroll
        for (int off = 1; off < 16; off <<= 1) {
            ssrc += __shfl_xor(ssrc, off);
            sdst += __shfl_xor(sdst, off);
        }
        if (lr == 0) {
            int row = m0 + lk * 4 + r;
            if (row < N) { s_src[row] = ssrc; s_dst[row] = sdst; }
        }
    }

    // repack D-frags -> bf16 rows (same-wave LDS, no barrier)
    #pragma unroll
    for (int t = 0; t < 4; ++t)
        #pragma unroll
        for (int r = 0; r < 4; ++r)
            pack[w][lk * 4 + r][t * 16 + lr] = f2bf(acc[t][r]);

    int prow = lane >> 2;                        // 0..15
    int pcol = (lane & 3) * 16;                  // 0,16,32,48
    int grow = m0 + prow;
    if (grow < N) {
        uint4 v0 = *(const uint4*)&pack[w][prow][pcol];
        uint4 v1 = *(const uint4*)&pack[w][prow][pcol + 8];
        *(uint4*)(Whb + (size_t)grow * DD + pcol)     = v0;
        *(uint4*)(Whb + (size_t)grow * DD + pcol + 8) = v1;
    }
}

// ---------------- Kernel 2: edge-parallel row_ptr boundary scatter -----------------
__global__ __launch_bounds__(256) void rowptr_kernel(
    const int* __restrict__ src, int* __restrict__ row_ptr, int E, int N)
{
    int i = blockIdx.x * 256 + threadIdx.x;
    if (i >= E) return;
    int s   = src[i];
    int nxt = (i + 1 < E) ? src[i + 1] : N;
    if (i == 0)
        for (int n = 0; n <= s; ++n) row_ptr[n] = 0;
    for (int n = s + 1; n <= nxt; ++n) row_ptr[n] = i + 1;
}

// ---------------- Kernel 3: 8-lane group, TWO nodes sequentially, 4-wide ILP -------
__global__ __launch_bounds__(256) void agg_kernel(
    const unsigned short* __restrict__ Whb, const float* __restrict__ s_src,
    const float* __restrict__ s_dst, const int* __restrict__ edge_dst,
    const int* __restrict__ row_ptr, float* __restrict__ out, int N, int H)
{
    int tid = blockIdx.x * 256 + threadIdx.x;
    int grp = tid >> 3;                          // group id in [0, H)
    int c8  = threadIdx.x & 7;                   // this lane owns feats c8*8..c8*8+7
    if (grp >= H) return;

    for (int k = 0; k < 2; ++k) {
        int node = grp + k * H;
        if (node >= N) break;

        int lo = row_ptr[node], hi = row_ptr[node + 1];
        size_t obase = (size_t)node * DD;

        if (lo == hi) {                          // no outgoing edges: relu(Wh row)
            uint4 q = *(const uint4*)(Whb + obase + c8 * 8);
            float v[8] = {};
            fma8(1.f, q, v);
            float4 o0 = make_float4(fmaxf(v[0], 0.f), fmaxf(v[1], 0.f),
                                    fmaxf(v[2], 0.f), fmaxf(v[3], 0.f));
            float4 o1 = make_float4(fmaxf(v[4], 0.f), fmaxf(v[5], 0.f),
                                    fmaxf(v[6], 0.f), fmaxf(v[7], 0.f));
            ((float4*)(out + obase))[c8 * 2]     = o0;
            ((float4*)(out + obase))[c8 * 2 + 1] = o1;
            continue;
        }

        float ss    = s_src[node];
        float denom = 0.f;                       // identical in all 8 lanes
        float acc[8] = {};

        for (int e = lo; e < hi; e += 4) {       // 4 independent row-gathers in flight
            int i1 = (e + 1 < hi) ? e + 1 : hi - 1;   // clamp: dup loads, p forced 0
            int i2 = (e + 2 < hi) ? e + 2 : hi - 1;
            int i3 = (e + 3 < hi) ? e + 3 : hi - 1;
            int d0 = edge_dst[e],  d1 = edge_dst[i1];
            int d2 = edge_dst[i2], d3 = edge_dst[i3];
            float t0 = s_dst[d0], t1 = s_dst[d1], t2 = s_dst[d2], t3 = s_dst[d3];
            uint4 q0 = *(const uint4*)(Whb + (size_t)d0 * DD + c8 * 8);
            uint4 q1 = *(const uint4*)(Whb + (size_t)d1 * DD + c8 * 8);
            uint4 q2 = *(const uint4*)(Whb + (size_t)d2 * DD + c8 * 8);
            uint4 q3 = *(const uint4*)(Whb + (size_t)d3 * DD + c8 * 8);
            float x0 = ss + t0, x1 = ss + t1, x2 = ss + t2, x3 = ss + t3;
            x0 = x0 > 0.f ? x0 : 0.2f * x0;      // leaky_relu(0.2)
            x1 = x1 > 0.f ? x1 : 0.2f * x1;
            x2 = x2 > 0.f ? x2 : 0.2f * x2;
            x3 = x3 > 0.f ? x3 : 0.2f * x3;
            float p0 = __expf(x0);               // |e| small -> skip max-shift
            float p1 = (e + 1 < hi) ? __expf(x1) : 0.f;
            float p2 = (e + 2 < hi) ? __expf(x2) : 0.f;
            float p3 = (e + 3 < hi) ? __expf(x3) : 0.f;
            denom += (p0 + p1) + (p2 + p3);
            fma8(p0, q0, acc);
            fma8(p1, q1, acc);
            fma8(p2, q2, acc);
            fma8(p3, q3, acc);
        }

        float inv = 1.f / denom;
        float4 o0 = make_float4(fmaxf(acc[0] * inv, 0.f), fmaxf(acc[1] * inv, 0.f),
                                fmaxf(acc[2] * inv, 0.f), fmaxf(acc[3] * inv, 0.f));
        float4 o1 = make_float4(fmaxf(acc[4] * inv, 0.f), fmaxf(acc[5] * inv, 0.f),
                                fmaxf(acc[6] * inv, 0.f), fmaxf(acc[7] * inv, 0.f));
        ((float4*)(out + obase))[c8 * 2]     = o0;
        ((float4*)(out + obase))[c8 * 2 + 1] = o1;
    }
}

// ---------------- launch ----------------
extern "C" void kernel_launch(void* const* d_in, const int* in_sizes, int n_in,
                              void* d_out, int out_size, void* d_ws, size_t ws_size,
                              hipStream_t stream)
{
    const float* h    = (const float*)d_in[0];
    const float* W    = (const float*)d_in[1];
    const float* a    = (const float*)d_in[2];
    const int*   esrc = (const int*)d_in[3];
    const int*   edst = (const int*)d_in[4];

    int N = in_sizes[0] / DD;
    int E = in_sizes[3];
    float* out = (float*)d_out;

    // ws layout: Whb (N*64 bf16) | s_src (N f32) | s_dst (N f32) | row_ptr (N+1)
    unsigned short* Whb = (unsigned short*)d_ws;          // 12.8 MB
    float* s_src   = (float*)(Whb + (size_t)N * DD);      // 0.4 MB
    float* s_dst   = s_src + N;                           // 0.4 MB
    int*   row_ptr = (int*)(s_dst + N);                   // 0.4 MB

    wh_kernel<<<(N + 63) / 64, 256, 0, stream>>>(h, W, a, Whb, s_src, s_dst, N);
    rowptr_kernel<<<(E + 255) / 256, 256, 0, stream>>>(esrc, row_ptr, E, N);
    int H = (N + 1) / 2;                                  // two nodes per group
    int aggThreads = H * 8;
    agg_kernel<<<(aggThreads + 255) / 256, 256, 0, stream>>>(Whb, s_src, s_dst, edst, row_ptr, out, N, H);
}

// Round 14
// 52.480 us; speedup vs baseline: 1.2529x; 1.2529x over previous
//
#include <hip/hip_runtime.h>
#include <math.h>

// GAT aggregator: out = relu( deg>0 ? segment_softmax(leaky(s_src[src]+s_dst[dst])) @ Wh[dst] : Wh )
// N=100000, E=1600000, D=64. edge_src is SORTED.
// wh: bf16 MFMA; W staged ONCE PER BLOCK into LDS (kills 400MB of per-wave W re-reads).
// agg: R9 best structure — one 8-lane group per node, 4-wide ILP, bf16 rows.

#define DD 64

typedef __attribute__((ext_vector_type(8))) short bf16x8;
typedef __attribute__((ext_vector_type(4))) float f32x4;

static __device__ __forceinline__ unsigned short f2bf(float x) {
    unsigned int u = __float_as_uint(x);
    u += 0x7fffu + ((u >> 16) & 1u);          // RNE
    return (unsigned short)(u >> 16);
}

static __device__ __forceinline__ bf16x8 cvt8(float4 x0, float4 x1) {
    bf16x8 f;
    f[0] = (short)f2bf(x0.x); f[1] = (short)f2bf(x0.y);
    f[2] = (short)f2bf(x0.z); f[3] = (short)f2bf(x0.w);
    f[4] = (short)f2bf(x1.x); f[5] = (short)f2bf(x1.y);
    f[6] = (short)f2bf(x1.z); f[7] = (short)f2bf(x1.w);
    return f;
}

static __device__ __forceinline__ void fma8(float p, uint4 q, float* acc) {
    acc[0] = fmaf(p, __uint_as_float(q.x << 16),          acc[0]);
    acc[1] = fmaf(p, __uint_as_float(q.x & 0xffff0000u),  acc[1]);
    acc[2] = fmaf(p, __uint_as_float(q.y << 16),          acc[2]);
    acc[3] = fmaf(p, __uint_as_float(q.y & 0xffff0000u),  acc[3]);
    acc[4] = fmaf(p, __uint_as_float(q.z << 16),          acc[4]);
    acc[5] = fmaf(p, __uint_as_float(q.z & 0xffff0000u),  acc[5]);
    acc[6] = fmaf(p, __uint_as_float(q.w << 16),          acc[6]);
    acc[7] = fmaf(p, __uint_as_float(q.w & 0xffff0000u),  acc[7]);
}

// ---------------- Kernel 1: Whb = bf16(h @ W^T) via MFMA; W via LDS ---------------
__global__ __launch_bounds__(256) void wh_kernel(
    const float* __restrict__ h, const float* __restrict__ W,
    const float* __restrict__ a, unsigned short* __restrict__ Whb,
    float* __restrict__ s_src, float* __restrict__ s_dst, int N)
{
    __shared__ unsigned short Wsh[64][64];       // bf16 W, 8KB, staged once per block
    __shared__ unsigned short pack[4][16][72];   // per-wave repack buffer

    int t = threadIdx.x;

    // stage W -> LDS (1024 float4s; 4 per thread; coalesced; conflict-free writes)
    #pragma unroll
    for (int c = 0; c < 4; ++c) {
        int idx = c * 256 + t;                   // float4 index 0..1023
        int row = idx >> 4;                      // 0..63
        int c4  = idx & 15;                      // float4 within row
        float4 v = ((const float4*)W)[idx];
        unsigned short b[4] = {f2bf(v.x), f2bf(v.y), f2bf(v.z), f2bf(v.w)};
        *(uint2*)&Wsh[row][c4 * 4] = *(const uint2*)b;
    }
    __syncthreads();

    int w    = threadIdx.x >> 6;
    int lane = threadIdx.x & 63;
    int lr   = lane & 15;                        // row-in-tile (A) / col-in-tile (B,D)
    int lk   = lane >> 4;                        // k-group (A,B) / row-group (D)
    int m0   = blockIdx.x * 64 + w * 16;
    if (m0 >= N) return;                         // after barrier; wave-uniform

    // B-frags from LDS: lane (lr,lk) reads W[t*16+lr][q*32+lk*8 .. +8] (16B aligned)
    bf16x8 bfr[4][2];
    #pragma unroll
    for (int tt = 0; tt < 4; ++tt)
        #pragma unroll
        for (int q = 0; q < 2; ++q)
            bfr[tt][q] = *(const bf16x8*)&Wsh[tt * 16 + lr][q * 32 + lk * 8];

    // A-frags: this wave's 16 h rows (global, each row read once per block)
    int arow = m0 + lr; if (arow >= N) arow = N - 1;
    const float* hrow = h + (size_t)arow * DD;
    bf16x8 afr[2];
    #pragma unroll
    for (int q = 0; q < 2; ++q) {
        float4 x0 = *(const float4*)(hrow + q * 32 + lk * 8);
        float4 x1 = *(const float4*)(hrow + q * 32 + lk * 8 + 4);
        afr[q] = cvt8(x0, x1);
    }

    // 8 MFMA: 4 col-tiles x K=64
    f32x4 acc[4];
    #pragma unroll
    for (int tt = 0; tt < 4; ++tt) {
        f32x4 z = {0.f, 0.f, 0.f, 0.f};
        z = __builtin_amdgcn_mfma_f32_16x16x32_bf16(afr[0], bfr[tt][0], z, 0, 0, 0);
        acc[tt] = __builtin_amdgcn_mfma_f32_16x16x32_bf16(afr[1], bfr[tt][1], z, 0, 0, 0);
    }

    // scores: lane has col = t*16+lr, rows lk*4+r
    float av0[4], av1[4];
    #pragma unroll
    for (int tt = 0; tt < 4; ++tt) {
        av0[tt] = a[tt * 16 + lr];
        av1[tt] = a[DD + tt * 16 + lr];
    }
    #pragma unroll
    for (int r = 0; r < 4; ++r) {
        float ssrc = 0.f, sdst = 0.f;
        #pragma unroll
        for (int tt = 0; tt < 4; ++tt) {
            ssrc = fmaf(acc[tt][r], av0[tt], ssrc);
            sdst = fmaf(acc[tt][r], av1[tt], sdst);
        }
        #pragma unroll
        for (int off = 1; off < 16; off <<= 1) {
            ssrc += __shfl_xor(ssrc, off);
            sdst += __shfl_xor(sdst, off);
        }
        if (lr == 0) {
            int row = m0 + lk * 4 + r;
            if (row < N) { s_src[row] = ssrc; s_dst[row] = sdst; }
        }
    }

    // repack D-frags -> bf16 rows (same-wave LDS region, no barrier needed)
    #pragma unroll
    for (int tt = 0; tt < 4; ++tt)
        #pragma unroll
        for (int r = 0; r < 4; ++r)
            pack[w][lk * 4 + r][tt * 16 + lr] = f2bf(acc[tt][r]);

    int prow = lane >> 2;                        // 0..15
    int pcol = (lane & 3) * 16;                  // 0,16,32,48
    int grow = m0 + prow;
    if (grow < N) {
        uint4 v0 = *(const uint4*)&pack[w][prow][pcol];
        uint4 v1 = *(const uint4*)&pack[w][prow][pcol + 8];
        *(uint4*)(Whb + (size_t)grow * DD + pcol)     = v0;
        *(uint4*)(Whb + (size_t)grow * DD + pcol + 8) = v1;
    }
}

// ---------------- Kernel 2: edge-parallel row_ptr boundary scatter -----------------
__global__ __launch_bounds__(256) void rowptr_kernel(
    const int* __restrict__ src, int* __restrict__ row_ptr, int E, int N)
{
    int i = blockIdx.x * 256 + threadIdx.x;
    if (i >= E) return;
    int s   = src[i];
    int nxt = (i + 1 < E) ? src[i + 1] : N;
    if (i == 0)
        for (int n = 0; n <= s; ++n) row_ptr[n] = 0;
    for (int n = s + 1; n <= nxt; ++n) row_ptr[n] = i + 1;
}

// ---------------- Kernel 3: one 8-lane group per node; fused, 4-wide ILP -----------
__global__ __launch_bounds__(256) void agg_kernel(
    const unsigned short* __restrict__ Whb, const float* __restrict__ s_src,
    const float* __restrict__ s_dst, const int* __restrict__ edge_dst,
    const int* __restrict__ row_ptr, float* __restrict__ out, int N)
{
    int tid  = blockIdx.x * 256 + threadIdx.x;
    int node = tid >> 3;                         // 8 lanes per node
    int c8   = threadIdx.x & 7;                  // this lane owns feats c8*8..c8*8+7
    if (node >= N) return;

    int lo = row_ptr[node], hi = row_ptr[node + 1];
    size_t obase = (size_t)node * DD;

    if (lo == hi) {                              // no outgoing edges: relu(Wh row)
        uint4 q = *(const uint4*)(Whb + obase + c8 * 8);
        float v[8] = {};
        fma8(1.f, q, v);
        float4 o0 = make_float4(fmaxf(v[0], 0.f), fmaxf(v[1], 0.f),
                                fmaxf(v[2], 0.f), fmaxf(v[3], 0.f));
        float4 o1 = make_float4(fmaxf(v[4], 0.f), fmaxf(v[5], 0.f),
                                fmaxf(v[6], 0.f), fmaxf(v[7], 0.f));
        ((float4*)(out + obase))[c8 * 2]     = o0;
        ((float4*)(out + obase))[c8 * 2 + 1] = o1;
        return;
    }

    float ss    = s_src[node];
    float denom = 0.f;                           // identical in all 8 lanes
    float acc[8] = {};

    for (int e = lo; e < hi; e += 4) {           // 4 independent row-gathers in flight
        int i1 = (e + 1 < hi) ? e + 1 : hi - 1;  // clamp: dup loads, p forced 0
        int i2 = (e + 2 < hi) ? e + 2 : hi - 1;
        int i3 = (e + 3 < hi) ? e + 3 : hi - 1;
        int d0 = edge_dst[e],  d1 = edge_dst[i1];
        int d2 = edge_dst[i2], d3 = edge_dst[i3];
        float t0 = s_dst[d0], t1 = s_dst[d1], t2 = s_dst[d2], t3 = s_dst[d3];
        uint4 q0 = *(const uint4*)(Whb + (size_t)d0 * DD + c8 * 8);
        uint4 q1 = *(const uint4*)(Whb + (size_t)d1 * DD + c8 * 8);
        uint4 q2 = *(const uint4*)(Whb + (size_t)d2 * DD + c8 * 8);
        uint4 q3 = *(const uint4*)(Whb + (size_t)d3 * DD + c8 * 8);
        float x0 = ss + t0, x1 = ss + t1, x2 = ss + t2, x3 = ss + t3;
        x0 = x0 > 0.f ? x0 : 0.2f * x0;          // leaky_relu(0.2)
        x1 = x1 > 0.f ? x1 : 0.2f * x1;
        x2 = x2 > 0.f ? x2 : 0.2f * x2;
        x3 = x3 > 0.f ? x3 : 0.2f * x3;
        float p0 = __expf(x0);                   // |e| small -> skip max-shift
        float p1 = (e + 1 < hi) ? __expf(x1) : 0.f;
        float p2 = (e + 2 < hi) ? __expf(x2) : 0.f;
        float p3 = (e + 3 < hi) ? __expf(x3) : 0.f;
        denom += (p0 + p1) + (p2 + p3);
        fma8(p0, q0, acc);
        fma8(p1, q1, acc);
        fma8(p2, q2, acc);
        fma8(p3, q3, acc);
    }

    float inv = 1.f / denom;
    float4 o0 = make_float4(fmaxf(acc[0] * inv, 0.f), fmaxf(acc[1] * inv, 0.f),
                            fmaxf(acc[2] * inv, 0.f), fmaxf(acc[3] * inv, 0.f));
    float4 o1 = make_float4(fmaxf(acc[4] * inv, 0.f), fmaxf(acc[5] * inv, 0.f),
                            fmaxf(acc[6] * inv, 0.f), fmaxf(acc[7] * inv, 0.f));
    ((float4*)(out + obase))[c8 * 2]     = o0;
    ((float4*)(out + obase))[c8 * 2 + 1] = o1;
}

// ---------------- launch ----------------
extern "C" void kernel_launch(void* const* d_in, const int* in_sizes, int n_in,
                              void* d_out, int out_size, void* d_ws, size_t ws_size,
                              hipStream_t stream)
{
    const float* h    = (const float*)d_in[0];
    const float* W    = (const float*)d_in[1];
    const float* a    = (const float*)d_in[2];
    const int*   esrc = (const int*)d_in[3];
    const int*   edst = (const int*)d_in[4];

    int N = in_sizes[0] / DD;
    int E = in_sizes[3];
    float* out = (float*)d_out;

    // ws layout: Whb (N*64 bf16) | s_src (N f32) | s_dst (N f32) | row_ptr (N+1)
    unsigned short* Whb = (unsigned short*)d_ws;          // 12.8 MB
    float* s_src   = (float*)(Whb + (size_t)N * DD);      // 0.4 MB
    float* s_dst   = s_src + N;                           // 0.4 MB
    int*   row_ptr = (int*)(s_dst + N);                   // 0.4 MB

    wh_kernel<<<(N + 63) / 64, 256, 0, stream>>>(h, W, a, Whb, s_src, s_dst, N);
    rowptr_kernel<<<(E + 255) / 256, 256, 0, stream>>>(esrc, row_ptr, E, N);
    int aggThreads = N * 8;
    agg_kernel<<<(aggThreads + 255) / 256, 256, 0, stream>>>(Whb, s_src, s_dst, edst, row_ptr, out, N);
}